// Round 6
// baseline (430.605 us; speedup 1.0000x reference)
//
#include <hip/hip_runtime.h>

#define NEG_SLOPE 0.2f
#define NGRAPHS 512

typedef short short8 __attribute__((ext_vector_type(8)));
typedef float f32x4 __attribute__((ext_vector_type(4)));

__device__ __forceinline__ float wave_reduce_sum(float v) {
#pragma unroll
    for (int off = 32; off > 0; off >>= 1) v += __shfl_xor(v, off, 64);
    return v;
}
__device__ __forceinline__ float wave_reduce_max(float v) {
#pragma unroll
    for (int off = 32; off > 0; off >>= 1) v = fmaxf(v, __shfl_xor(v, off, 64));
    return v;
}
__device__ __forceinline__ unsigned short f2bf(float f) {  // fp32 -> bf16 RNE
    unsigned u = __float_as_uint(f);
    u += 0x7FFFu + ((u >> 16) & 1u);
    return (unsigned short)(u >> 16);
}

__device__ __forceinline__ void edge_sd(const int* __restrict__ ei, int E, int e,
                                        int& s, int& d) {
    if (e < E) { s = ei[e]; d = ei[E + e]; }
    else { s = d = e - E; }  // appended self-loops
}

// ---- setup + histogram, block-specialized:
// blocks [0,nEdgeBlk): hist (also records rank-within-dst); [+64): convert W1;
// [+1): convert W2; [+1): bounds
__global__ __launch_bounds__(256) void setup_hist(
    const int* __restrict__ ei, int E, int ET, int* __restrict__ counts,
    int nEdgeBlk, const float* __restrict__ W1, unsigned short* __restrict__ Wt1,
    int K1, const float* __restrict__ W2, unsigned short* __restrict__ Wt2,
    const int* __restrict__ batch, int* __restrict__ gstart, int N,
    int* __restrict__ rank) {
    const int b = blockIdx.x, tid = threadIdx.x;
    if (b < nEdgeBlk) {
        int e = b * 256 + tid;
        if (e >= ET) return;
        int s, d;
        edge_sd(ei, E, e, s, d);
        rank[e] = atomicAdd(counts + d, 1);  // rank reused by fill_csr: no 2nd atomic pass
    } else if (b < nEdgeBlk + 64) {
        int n = b - nEdgeBlk;
        for (int k = tid; k < K1; k += 256)
            Wt1[(size_t)n * K1 + k] = f2bf(W1[(size_t)k * 64 + n]);
    } else if (b == nEdgeBlk + 64) {
#pragma unroll
        for (int i = 0; i < 16; ++i) {
            int idx = tid + i * 256;
            int n = idx >> 6, k = idx & 63;
            Wt2[n * 64 + k] = f2bf(W2[k * 64 + n]);
        }
    } else {
        for (int g = tid; g <= NGRAPHS; g += 256) {
            int lo = 0, hi = N;
            while (lo < hi) {
                int mid = (lo + hi) >> 1;
                if (batch[mid] < g) lo = mid + 1; else hi = mid;
            }
            gstart[g] = lo;
        }
    }
}

// per-block sums over chunks of CH
__global__ __launch_bounds__(256) void scan_sum(const int* __restrict__ counts,
                                                int* __restrict__ blk_sum, int N,
                                                int CH) {
    __shared__ int wsum[4];
    const int tid = threadIdx.x, lane = tid & 63, wid = tid >> 6;
    const int b = blockIdx.x;
    int begin = b * CH, endi = min(begin + CH, N);
    int s = 0;
    for (int i = begin + tid; i < endi; i += 256) s += counts[i];
#pragma unroll
    for (int off = 32; off > 0; off >>= 1) s += __shfl_xor(s, off, 64);
    if (lane == 0) wsum[wid] = s;
    __syncthreads();
    if (tid == 0) blk_sum[b] = wsum[0] + wsum[1] + wsum[2] + wsum[3];
}

// exclusive scan of 64 block sums (1 wave); also writes row_ptr[N]=total
__global__ __launch_bounds__(64) void scan_blk(int* __restrict__ blk_sum,
                                               int* __restrict__ row_ptr, int N,
                                               int nb) {
    int t = threadIdx.x;
    int v = (t < nb) ? blk_sum[t] : 0;
    int sv = v;
#pragma unroll
    for (int off = 1; off < 64; off <<= 1) {
        int u = __shfl_up(sv, off, 64);
        if (t >= off) sv += u;
    }
    if (t < nb) blk_sum[t] = sv - v;
    if (t == nb - 1) row_ptr[N] = sv;
}

// local exclusive scan with block offset; writes row_ptr
__global__ __launch_bounds__(256) void scan_local(const int* __restrict__ counts,
                                                  const int* __restrict__ blk_off,
                                                  int* __restrict__ row_ptr, int N,
                                                  int CH) {
    __shared__ int wsum[4];
    __shared__ int ctot;
    const int tid = threadIdx.x, lane = tid & 63, wid = tid >> 6;
    const int b = blockIdx.x;
    int begin = b * CH, endi = min(begin + CH, N);
    int carry = blk_off[b];
    for (int base = begin; base < endi; base += 256) {
        int i = base + tid;
        int v = (i < endi) ? counts[i] : 0;
        int sv = v;
#pragma unroll
        for (int off = 1; off < 64; off <<= 1) {
            int u = __shfl_up(sv, off, 64);
            if (lane >= off) sv += u;
        }
        if (lane == 63) wsum[wid] = sv;
        __syncthreads();
        if (tid == 0) {
            int a = 0;
#pragma unroll
            for (int j = 0; j < 4; ++j) { int u = wsum[j]; wsum[j] = a; a += u; }
            ctot = a;
        }
        __syncthreads();
        int excl = carry + wsum[wid] + sv - v;
        if (i < endi) row_ptr[i] = excl;
        carry += ctot;
        __syncthreads();
    }
}

// ---- CSR fill, atomic-free: pos = row_ptr[dst] + rank (from hist pass) ----
__global__ __launch_bounds__(256) void fill_csr(const int* __restrict__ ei, int E,
                                                int ET,
                                                const int* __restrict__ row_ptr,
                                                const int* __restrict__ rank,
                                                int* __restrict__ srcs) {
    int e = blockIdx.x * 256 + threadIdx.x;
    if (e >= ET) return;
    int s, d;
    edge_sd(ei, E, e, s, d);
    srcs[row_ptr[d] + rank[e]] = s;
}

// ---- Layer-1 GEMM (bf16 MFMA) + fused att epilogue. Coalesced staging +
// software pipeline (T14-style): loads for chunk c+1 are issued (to regs)
// right after the barrier, pinned ahead of MFMA(c) by sched_barrier(0), so
// HBM latency hides under the MFMA phase + next barrier. Loads are
// unconditional (clamped rows) so the compiler can keep them hoisted -- the
// R1 failure was divergent-guarded loads being re-sunk.
__global__ __launch_bounds__(256, 4) void gemm1_mfma(
    const float* __restrict__ A, const unsigned short* __restrict__ Wt, int M,
    int K, float* __restrict__ h, const float* __restrict__ att_s,
    const float* __restrict__ att_d, float* __restrict__ a_s,
    float* __restrict__ a_d) {
    __shared__ unsigned short As[64][136];  // A chunk, bf16 (17.4 KB)
    __shared__ unsigned short Bs[64][136];  // B chunk, bf16 (17.4 KB)
    const int tid = threadIdx.x;
    const int w = tid >> 6, l = tid & 63, m = l & 15, q = l >> 4;
    const int row0 = blockIdx.x * 64;
    // A staging: 64 rows x 128 fp32/chunk; wave = 2 contiguous 512B spans.
    const int sr = tid >> 5;   // 0..7
    const int sc4 = tid & 31;  // float4 within 128-float row-slice
    int srow[8];
#pragma unroll
    for (int i = 0; i < 8; ++i) {
        int r = row0 + sr + i * 8;
        srow[i] = r < M ? r : M - 1;  // clamp; garbage rows are store-masked
    }
    // B staging: 64 rows x 128 bf16/chunk; wave = 4 contiguous 256B spans.
    const int br = tid >> 4;   // 0..15
    const int bcu = tid & 15;  // uint4 (8 bf16) within row-slice
    f32x4 acc0 = {0.f, 0.f, 0.f, 0.f}, acc1 = acc0, acc2 = acc0, acc3 = acc0;
    float4 abuf[8];
    uint4 bbuf[4];
    // prologue: chunk 0 -> regs
#pragma unroll
    for (int i = 0; i < 8; ++i)
        abuf[i] = *(const float4*)(A + (size_t)srow[i] * K + sc4 * 4);
#pragma unroll
    for (int i = 0; i < 4; ++i)
        bbuf[i] = *(const uint4*)(Wt + (size_t)(br + i * 16) * K + bcu * 8);
#pragma unroll 1
    for (int c = 0; c < 6; ++c) {  // K = 768 = 6 chunks of 128
        // write staged regs -> LDS
#pragma unroll
        for (int i = 0; i < 8; ++i) {
            unsigned short t4[4] = {f2bf(abuf[i].x), f2bf(abuf[i].y),
                                    f2bf(abuf[i].z), f2bf(abuf[i].w)};
            *(uint2*)&As[sr + i * 8][sc4 * 4] = *(uint2*)t4;
        }
#pragma unroll
        for (int i = 0; i < 4; ++i)
            *(uint4*)&Bs[br + i * 16][bcu * 8] = bbuf[i];
        __syncthreads();
        if (c < 5) {  // issue next chunk's loads; results needed next iter only
#pragma unroll
            for (int i = 0; i < 8; ++i)
                abuf[i] = *(const float4*)(A + (size_t)srow[i] * K +
                                           (c + 1) * 128 + sc4 * 4);
#pragma unroll
            for (int i = 0; i < 4; ++i)
                bbuf[i] = *(const uint4*)(Wt + (size_t)(br + i * 16) * K +
                                          (c + 1) * 128 + bcu * 8);
        }
        __builtin_amdgcn_sched_barrier(0);  // pin prefetch issue ahead of MFMA
        const unsigned short* arow = &As[w * 16 + m][0];
        const unsigned short* brow = &Bs[m][0];
#pragma unroll
        for (int ks = 0; ks < 4; ++ks) {
            short8 av = *(const short8*)(arow + ks * 32 + q * 8);
            const int bo = ks * 32 + q * 8;
            acc0 = __builtin_amdgcn_mfma_f32_16x16x32_bf16(
                av, *(const short8*)(brow + bo), acc0, 0, 0, 0);
            acc1 = __builtin_amdgcn_mfma_f32_16x16x32_bf16(
                av, *(const short8*)(brow + 16 * 136 + bo), acc1, 0, 0, 0);
            acc2 = __builtin_amdgcn_mfma_f32_16x16x32_bf16(
                av, *(const short8*)(brow + 32 * 136 + bo), acc2, 0, 0, 0);
            acc3 = __builtin_amdgcn_mfma_f32_16x16x32_bf16(
                av, *(const short8*)(brow + 48 * 136 + bo), acc3, 0, 0, 0);
        }
        __syncthreads();
    }
    // epilogue: C/D layout col=lane&15, row=q*4+reg
    float as0 = att_s[m], as1 = att_s[16 + m], as2 = att_s[32 + m], as3 = att_s[48 + m];
    float ad0 = att_d[m], ad1 = att_d[16 + m], ad2 = att_d[32 + m], ad3 = att_d[48 + m];
    const int rowb = row0 + w * 16 + q * 4;
#pragma unroll
    for (int rr = 0; rr < 4; ++rr) {
        int row = rowb + rr;
        float v0 = acc0[rr], v1 = acc1[rr], v2 = acc2[rr], v3 = acc3[rr];
        if (row < M) {
            float* hp = h + (size_t)row * 64 + m;
            hp[0] = v0; hp[16] = v1; hp[32] = v2; hp[48] = v3;
        }
        float hs = v0 * as0 + v1 * as1 + v2 * as2 + v3 * as3;
        float hd = v0 * ad0 + v1 * ad1 + v2 * ad2 + v3 * ad3;
#pragma unroll
        for (int off = 1; off < 16; off <<= 1) {
            hs += __shfl_xor(hs, off, 64);
            hd += __shfl_xor(hd, off, 64);
        }
        if (m == 0 && row < M) { a_s[row] = hs; a_d[row] = hd; }
    }
}

// ---- Layer-2 GEMM: bf16 MFMA, K=64, no LDS (frags from L2) + fused att ----
__global__ __launch_bounds__(256) void gemm2_mfma(
    const unsigned short* __restrict__ Ab, const unsigned short* __restrict__ Wt2,
    int M, float* __restrict__ h, const float* __restrict__ att_s,
    const float* __restrict__ att_d, float* __restrict__ a_s,
    float* __restrict__ a_d) {
    const int tid = threadIdx.x;
    const int w = tid >> 6, l = tid & 63, m = l & 15, q = l >> 4;
    const int row0 = blockIdx.x * 64;
    const int r = row0 + w * 16 + m;  // A-frag row
    short8 av0 = {0, 0, 0, 0, 0, 0, 0, 0}, av1 = av0;
    if (r < M) {
        av0 = *(const short8*)(Ab + (size_t)r * 64 + q * 8);
        av1 = *(const short8*)(Ab + (size_t)r * 64 + 32 + q * 8);
    }
    f32x4 acc0 = {0.f, 0.f, 0.f, 0.f}, acc1 = acc0, acc2 = acc0, acc3 = acc0;
    const unsigned short* bp = Wt2 + (size_t)m * 64 + q * 8;
    acc0 = __builtin_amdgcn_mfma_f32_16x16x32_bf16(av0, *(const short8*)(bp), acc0, 0, 0, 0);
    acc0 = __builtin_amdgcn_mfma_f32_16x16x32_bf16(av1, *(const short8*)(bp + 32), acc0, 0, 0, 0);
    acc1 = __builtin_amdgcn_mfma_f32_16x16x32_bf16(av0, *(const short8*)(bp + 16 * 64), acc1, 0, 0, 0);
    acc1 = __builtin_amdgcn_mfma_f32_16x16x32_bf16(av1, *(const short8*)(bp + 16 * 64 + 32), acc1, 0, 0, 0);
    acc2 = __builtin_amdgcn_mfma_f32_16x16x32_bf16(av0, *(const short8*)(bp + 32 * 64), acc2, 0, 0, 0);
    acc2 = __builtin_amdgcn_mfma_f32_16x16x32_bf16(av1, *(const short8*)(bp + 32 * 64 + 32), acc2, 0, 0, 0);
    acc3 = __builtin_amdgcn_mfma_f32_16x16x32_bf16(av0, *(const short8*)(bp + 48 * 64), acc3, 0, 0, 0);
    acc3 = __builtin_amdgcn_mfma_f32_16x16x32_bf16(av1, *(const short8*)(bp + 48 * 64 + 32), acc3, 0, 0, 0);

    float as0 = att_s[m], as1 = att_s[16 + m], as2 = att_s[32 + m], as3 = att_s[48 + m];
    float ad0 = att_d[m], ad1 = att_d[16 + m], ad2 = att_d[32 + m], ad3 = att_d[48 + m];
    const int rowb = row0 + w * 16 + q * 4;
#pragma unroll
    for (int rr = 0; rr < 4; ++rr) {
        int row = rowb + rr;
        float v0 = acc0[rr], v1 = acc1[rr], v2 = acc2[rr], v3 = acc3[rr];
        if (row < M) {
            float* hp = h + (size_t)row * 64 + m;
            hp[0] = v0; hp[16] = v1; hp[32] = v2; hp[48] = v3;
        }
        float hs = v0 * as0 + v1 * as1 + v2 * as2 + v3 * as3;
        float hd = v0 * ad0 + v1 * ad1 + v2 * ad2 + v3 * ad3;
#pragma unroll
        for (int off = 1; off < 16; off <<= 1) {
            hs += __shfl_xor(hs, off, 64);
            hd += __shfl_xor(hd, off, 64);
        }
        if (m == 0 && row < M) { a_s[row] = hs; a_d[row] = hd; }
    }
}

// ---- fused edge-softmax + aggregation + bias + relu: one wave per dst node.
// out (fp32) and outb (bf16) are each optional.
__global__ __launch_bounds__(256) void gat_agg_kernel(
    const int* __restrict__ row_ptr, const int* __restrict__ srcs,
    const float* __restrict__ a_s, const float* __restrict__ a_d,
    const float* __restrict__ h, const float* __restrict__ bias,
    float* __restrict__ out, unsigned short* __restrict__ outb, int N) {
    int n = blockIdx.x * 4 + (threadIdx.x >> 6);
    int lane = threadIdx.x & 63;
    if (n >= N) return;
    const int start = row_ptr[n];
    const int deg = row_ptr[n + 1] - start;
    const float adn = a_d[n];

    if (deg <= 64) {
        int sl = 0;
        float v = -1e30f;
        if (lane < deg) {
            sl = srcs[start + lane];
            float t = a_s[sl] + adn;
            v = (t >= 0.f) ? t : NEG_SLOPE * t;
        }
        float m = wave_reduce_max(v);
        float wl = (lane < deg) ? __expf(v - m) : 0.f;
        float l = wave_reduce_sum(wl);
        wl *= (1.f / l);

        const int eq = lane >> 4, fq = lane & 15;
        float ax = 0.f, ay = 0.f, az = 0.f, aw = 0.f;
        for (int j = 0; j < deg; j += 4) {
            int idx = j + eq;
            bool ok = idx < deg;
            int ii = ok ? idx : 0;
            float a = __shfl(wl, ii, 64);
            int s = __shfl(sl, ii, 64);
            if (!ok) a = 0.f;
            const float4 hv = *(const float4*)(h + (size_t)s * 64 + fq * 4);
            ax += a * hv.x; ay += a * hv.y; az += a * hv.z; aw += a * hv.w;
        }
#pragma unroll
        for (int off = 16; off <= 32; off <<= 1) {
            ax += __shfl_xor(ax, off, 64);
            ay += __shfl_xor(ay, off, 64);
            az += __shfl_xor(az, off, 64);
            aw += __shfl_xor(aw, off, 64);
        }
        if (eq == 0) {
            const float4 bv = *(const float4*)(bias + fq * 4);
            float4 o;
            o.x = ax + bv.x; o.y = ay + bv.y; o.z = az + bv.z; o.w = aw + bv.w;
            o.x = o.x > 0.f ? o.x : 0.f;
            o.y = o.y > 0.f ? o.y : 0.f;
            o.z = o.z > 0.f ? o.z : 0.f;
            o.w = o.w > 0.f ? o.w : 0.f;
            if (out) *(float4*)(out + (size_t)n * 64 + fq * 4) = o;
            if (outb) {
                unsigned short t[4] = {f2bf(o.x), f2bf(o.y), f2bf(o.z), f2bf(o.w)};
                *(uint2*)(outb + (size_t)n * 64 + fq * 4) = *(uint2*)t;
            }
        }
        return;
    }

    // general path (deg > 64)
    const int end = start + deg;
    float m = -1e30f;
    for (int i = start + lane; i < end; i += 64) {
        float v = a_s[srcs[i]] + adn;
        v = (v >= 0.f) ? v : NEG_SLOPE * v;
        m = fmaxf(m, v);
    }
    m = wave_reduce_max(m);
    float l = 0.f;
    for (int i = start + lane; i < end; i += 64) {
        float v = a_s[srcs[i]] + adn;
        v = (v >= 0.f) ? v : NEG_SLOPE * v;
        l += __expf(v - m);
    }
    l = wave_reduce_sum(l);
    const float inv_den = 1.f / l;
    float acc = 0.f;
    for (int c = start; c < end; c += 64) {
        int cl = end - c;
        if (cl > 64) cl = 64;
        int sl = 0;
        float wl = 0.f;
        if (c + lane < end) {
            sl = srcs[c + lane];
            float v = a_s[sl] + adn;
            v = (v >= 0.f) ? v : NEG_SLOPE * v;
            wl = __expf(v - m) * inv_den;
        }
        for (int j = 0; j < cl; ++j) {
            float wj = __shfl(wl, j, 64);
            int sj = __shfl(sl, j, 64);
            acc += wj * h[(size_t)sj * 64 + lane];
        }
    }
    float o = acc + bias[lane];
    o = o > 0.f ? o : 0.f;
    if (out) out[(size_t)n * 64 + lane] = o;
    if (outb) outb[(size_t)n * 64 + lane] = f2bf(o);
}

// ---- fused mean-pool + final linear: one block (4 waves) per graph ----
__global__ __launch_bounds__(256) void pool_final(const float* __restrict__ x,
                                                  const int* __restrict__ gstart,
                                                  const float* __restrict__ Wlin,
                                                  const float* __restrict__ blin,
                                                  float* __restrict__ out) {
    __shared__ float red[4][64];
    const int g = blockIdx.x;
    const int lane = threadIdx.x & 63, w = threadIdx.x >> 6;
    const int s = gstart[g], e = gstart[g + 1];
    float acc = 0.f;
    for (int n = s + w; n < e; n += 4) acc += x[(size_t)n * 64 + lane];
    red[w][lane] = acc;
    __syncthreads();
    if (w == 0) {
        float p = red[0][lane] + red[1][lane] + red[2][lane] + red[3][lane];
        int c = e - s;
        p /= (float)(c > 1 ? c : 1);
        float o0 = wave_reduce_sum(p * Wlin[lane * 2 + 0]);
        float o1 = wave_reduce_sum(p * Wlin[lane * 2 + 1]);
        if (lane == 0) {
            out[g * 2 + 0] = o0 + blin[0];
            out[g * 2 + 1] = o1 + blin[1];
        }
    }
}

extern "C" void kernel_launch(void* const* d_in, const int* in_sizes, int n_in,
                              void* d_out, int out_size, void* d_ws, size_t ws_size,
                              hipStream_t stream) {
    const float* x    = (const float*)d_in[0];
    const int*   ei   = (const int*)d_in[1];
    const int*   batch= (const int*)d_in[2];
    const float* W1   = (const float*)d_in[3];
    const float* as1  = (const float*)d_in[4];
    const float* ad1  = (const float*)d_in[5];
    const float* b1   = (const float*)d_in[6];
    const float* W2   = (const float*)d_in[7];
    const float* as2  = (const float*)d_in[8];
    const float* ad2  = (const float*)d_in[9];
    const float* b2   = (const float*)d_in[10];
    const float* Wlin = (const float*)d_in[11];
    const float* blin = (const float*)d_in[12];
    float* out = (float*)d_out;

    const int FIN = 768;
    const int N  = in_sizes[0] / FIN;   // 50000
    const int E  = in_sizes[1] / 2;     // 800000
    const int ET = E + N;
    const size_t N64 = (size_t)N * 64;
    const int NB = 64;                  // scan blocks
    const int CH = (N + NB - 1) / NB;

    float* ws     = (float*)d_ws;
    float* hbuf   = ws;                          // N*64 f32 (h1, then h2)
    float* x2     = hbuf + N64;                  // N*64 f32 (layer-2 output)
    float* a_s    = x2 + N64;                    // N
    float* a_d    = a_s + N;                     // N
    int* counts   = (int*)(a_d + N);             // N (zeroed)
    int* row_ptr  = counts + N;                  // N+1
    int* blk_sum  = row_ptr + N + 1;             // 64
    int* gstart   = blk_sum + 64;                // NGRAPHS+1
    int* srcs     = gstart + NGRAPHS + 1;        // ET
    int* rank     = srcs + ET;                   // ET
    uintptr_t wtp = (uintptr_t)(rank + ET);
    wtp = (wtp + 15) & ~(uintptr_t)15;
    unsigned short* Wt1 = (unsigned short*)wtp;          // 64*768 bf16
    unsigned short* Wt2 = Wt1 + (size_t)64 * FIN;        // 64*64 bf16
    unsigned short* x1b = Wt2 + (size_t)64 * 64;         // N*64 bf16 (layer-1 out)

    const int nEdgeBlk  = (ET + 255) / 256;
    const int nWaveBlkN = (N + 3) / 4;
    const int nGemmBlk  = (N + 63) / 64;

    hipMemsetAsync(counts, 0, (size_t)N * sizeof(int), stream);

    // ---- setup (W converts, graph bounds) + edge histogram + rank ----
    setup_hist<<<nEdgeBlk + 66, 256, 0, stream>>>(ei, E, ET, counts, nEdgeBlk,
                                                  W1, Wt1, FIN, W2, Wt2,
                                                  batch, gstart, N, rank);
    // ---- row_ptr scan ----
    scan_sum<<<NB, 256, 0, stream>>>(counts, blk_sum, N, CH);
    scan_blk<<<1, 64, 0, stream>>>(blk_sum, row_ptr, N, NB);
    scan_local<<<NB, 256, 0, stream>>>(counts, blk_sum, row_ptr, N, CH);

    // ---- CSR fill (atomic-free) ----
    fill_csr<<<nEdgeBlk, 256, 0, stream>>>(ei, E, ET, row_ptr, rank, srcs);

    // ---- Layer-1 MFMA gemm (coalesced, software-pipelined) + fused att ----
    gemm1_mfma<<<nGemmBlk, 256, 0, stream>>>(x, Wt1, N, FIN, hbuf, as1, ad1,
                                             a_s, a_d);
    gat_agg_kernel<<<nWaveBlkN, 256, 0, stream>>>(row_ptr, srcs, a_s, a_d, hbuf,
                                                  b1, nullptr, x1b, N);

    // ---- Layer-2 MFMA gemm (bf16, no LDS) + fused att ----
    gemm2_mfma<<<nGemmBlk, 256, 0, stream>>>(x1b, Wt2, N, hbuf, as2, ad2, a_s, a_d);
    gat_agg_kernel<<<nWaveBlkN, 256, 0, stream>>>(row_ptr, srcs, a_s, a_d, hbuf,
                                                  b2, x2, nullptr, N);

    // ---- Pool + final linear ----
    pool_final<<<NGRAPHS, 256, 0, stream>>>(x2, gstart, Wlin, blin, out);
}

// Round 7
// 403.590 us; speedup vs baseline: 1.0669x; 1.0669x over previous
//
#include <hip/hip_runtime.h>
#include <hip/hip_fp16.h>

#define NEG_SLOPE 0.2f
#define NGRAPHS 512

typedef short short8 __attribute__((ext_vector_type(8)));
typedef float f32x4 __attribute__((ext_vector_type(4)));

__device__ __forceinline__ float wave_reduce_sum(float v) {
#pragma unroll
    for (int off = 32; off > 0; off >>= 1) v += __shfl_xor(v, off, 64);
    return v;
}
__device__ __forceinline__ float wave_reduce_max(float v) {
#pragma unroll
    for (int off = 32; off > 0; off >>= 1) v = fmaxf(v, __shfl_xor(v, off, 64));
    return v;
}
__device__ __forceinline__ unsigned short f2bf(float f) {  // fp32 -> bf16 RNE
    unsigned u = __float_as_uint(f);
    u += 0x7FFFu + ((u >> 16) & 1u);
    return (unsigned short)(u >> 16);
}

__device__ __forceinline__ void edge_sd(const int* __restrict__ ei, int E, int e,
                                        int& s, int& d) {
    if (e < E) { s = ei[e]; d = ei[E + e]; }
    else { s = d = e - E; }  // appended self-loops
}

// ---- setup + histogram, block-specialized:
// blocks [0,nEdgeBlk): hist (also records rank-within-dst); [+64): convert W1;
// [+1): convert W2; [+1): bounds
__global__ __launch_bounds__(256) void setup_hist(
    const int* __restrict__ ei, int E, int ET, int* __restrict__ counts,
    int nEdgeBlk, const float* __restrict__ W1, unsigned short* __restrict__ Wt1,
    int K1, const float* __restrict__ W2, unsigned short* __restrict__ Wt2,
    const int* __restrict__ batch, int* __restrict__ gstart, int N,
    int* __restrict__ rank) {
    const int b = blockIdx.x, tid = threadIdx.x;
    if (b < nEdgeBlk) {
        int e = b * 256 + tid;
        if (e >= ET) return;
        int s, d;
        edge_sd(ei, E, e, s, d);
        rank[e] = atomicAdd(counts + d, 1);  // rank reused by fill_csr: no 2nd atomic pass
    } else if (b < nEdgeBlk + 64) {
        int n = b - nEdgeBlk;
        for (int k = tid; k < K1; k += 256)
            Wt1[(size_t)n * K1 + k] = f2bf(W1[(size_t)k * 64 + n]);
    } else if (b == nEdgeBlk + 64) {
#pragma unroll
        for (int i = 0; i < 16; ++i) {
            int idx = tid + i * 256;
            int n = idx >> 6, k = idx & 63;
            Wt2[n * 64 + k] = f2bf(W2[k * 64 + n]);
        }
    } else {
        for (int g = tid; g <= NGRAPHS; g += 256) {
            int lo = 0, hi = N;
            while (lo < hi) {
                int mid = (lo + hi) >> 1;
                if (batch[mid] < g) lo = mid + 1; else hi = mid;
            }
            gstart[g] = lo;
        }
    }
}

// per-block sums over chunks of CH
__global__ __launch_bounds__(256) void scan_sum(const int* __restrict__ counts,
                                                int* __restrict__ blk_sum, int N,
                                                int CH) {
    __shared__ int wsum[4];
    const int tid = threadIdx.x, lane = tid & 63, wid = tid >> 6;
    const int b = blockIdx.x;
    int begin = b * CH, endi = min(begin + CH, N);
    int s = 0;
    for (int i = begin + tid; i < endi; i += 256) s += counts[i];
#pragma unroll
    for (int off = 32; off > 0; off >>= 1) s += __shfl_xor(s, off, 64);
    if (lane == 0) wsum[wid] = s;
    __syncthreads();
    if (tid == 0) blk_sum[b] = wsum[0] + wsum[1] + wsum[2] + wsum[3];
}

// exclusive scan of 64 block sums (1 wave); also writes row_ptr[N]=total
__global__ __launch_bounds__(64) void scan_blk(int* __restrict__ blk_sum,
                                               int* __restrict__ row_ptr, int N,
                                               int nb) {
    int t = threadIdx.x;
    int v = (t < nb) ? blk_sum[t] : 0;
    int sv = v;
#pragma unroll
    for (int off = 1; off < 64; off <<= 1) {
        int u = __shfl_up(sv, off, 64);
        if (t >= off) sv += u;
    }
    if (t < nb) blk_sum[t] = sv - v;
    if (t == nb - 1) row_ptr[N] = sv;
}

// local exclusive scan with block offset; writes row_ptr
__global__ __launch_bounds__(256) void scan_local(const int* __restrict__ counts,
                                                  const int* __restrict__ blk_off,
                                                  int* __restrict__ row_ptr, int N,
                                                  int CH) {
    __shared__ int wsum[4];
    __shared__ int ctot;
    const int tid = threadIdx.x, lane = tid & 63, wid = tid >> 6;
    const int b = blockIdx.x;
    int begin = b * CH, endi = min(begin + CH, N);
    int carry = blk_off[b];
    for (int base = begin; base < endi; base += 256) {
        int i = base + tid;
        int v = (i < endi) ? counts[i] : 0;
        int sv = v;
#pragma unroll
        for (int off = 1; off < 64; off <<= 1) {
            int u = __shfl_up(sv, off, 64);
            if (lane >= off) sv += u;
        }
        if (lane == 63) wsum[wid] = sv;
        __syncthreads();
        if (tid == 0) {
            int a = 0;
#pragma unroll
            for (int j = 0; j < 4; ++j) { int u = wsum[j]; wsum[j] = a; a += u; }
            ctot = a;
        }
        __syncthreads();
        int excl = carry + wsum[wid] + sv - v;
        if (i < endi) row_ptr[i] = excl;
        carry += ctot;
        __syncthreads();
    }
}

// ---- CSR fill, atomic-free: pos = row_ptr[dst] + rank (from hist pass) ----
__global__ __launch_bounds__(256) void fill_csr(const int* __restrict__ ei, int E,
                                                int ET,
                                                const int* __restrict__ row_ptr,
                                                const int* __restrict__ rank,
                                                int* __restrict__ srcs) {
    int e = blockIdx.x * 256 + threadIdx.x;
    if (e >= ET) return;
    int s, d;
    edge_sd(ei, E, e, s, d);
    srcs[row_ptr[d] + rank[e]] = s;
}

// ---- Layer-1 GEMM (bf16 MFMA) + fused att epilogue. COALESCED staging
// (R5 structure -- the R6 sched_barrier pipeline regressed and is reverted).
// h is written in FP16 (halves the agg gather bytes; fp16's 10 mantissa bits
// add ~4x less rounding than bf16 would).
__global__ __launch_bounds__(256, 4) void gemm1_mfma(
    const float* __restrict__ A, const unsigned short* __restrict__ Wt, int M,
    int K, __half* __restrict__ h, const float* __restrict__ att_s,
    const float* __restrict__ att_d, float* __restrict__ a_s,
    float* __restrict__ a_d) {
    __shared__ unsigned short As[64][136];  // A chunk, bf16 (17.4 KB)
    __shared__ unsigned short Bs[64][136];  // B chunk, bf16 (17.4 KB)
    const int tid = threadIdx.x;
    const int w = tid >> 6, l = tid & 63, m = l & 15, q = l >> 4;
    const int row0 = blockIdx.x * 64;
    // A staging: 64 rows x 128 fp32/chunk; wave = 2 contiguous 512B spans.
    const int sr = tid >> 5;   // 0..7
    const int sc4 = tid & 31;  // float4 within 128-float row-slice
    int srow[8];
#pragma unroll
    for (int i = 0; i < 8; ++i) {
        int r = row0 + sr + i * 8;
        srow[i] = r < M ? r : M - 1;  // clamp; garbage rows are store-masked
    }
    // B staging: 64 rows x 128 bf16/chunk; wave = 4 contiguous 256B spans.
    const int br = tid >> 4;   // 0..15
    const int bcu = tid & 15;  // uint4 (8 bf16) within row-slice
    f32x4 acc0 = {0.f, 0.f, 0.f, 0.f}, acc1 = acc0, acc2 = acc0, acc3 = acc0;
#pragma unroll 1
    for (int c = 0; c < 6; ++c) {  // K = 768 = 6 chunks of 128
        float4 abuf[8];
#pragma unroll
        for (int i = 0; i < 8; ++i)
            abuf[i] = *(const float4*)(A + (size_t)srow[i] * K + c * 128 + sc4 * 4);
        uint4 bbuf[4];
#pragma unroll
        for (int i = 0; i < 4; ++i)
            bbuf[i] = *(const uint4*)(Wt + (size_t)(br + i * 16) * K + c * 128 + bcu * 8);
#pragma unroll
        for (int i = 0; i < 8; ++i) {
            unsigned short t4[4] = {f2bf(abuf[i].x), f2bf(abuf[i].y),
                                    f2bf(abuf[i].z), f2bf(abuf[i].w)};
            *(uint2*)&As[sr + i * 8][sc4 * 4] = *(uint2*)t4;
        }
#pragma unroll
        for (int i = 0; i < 4; ++i)
            *(uint4*)&Bs[br + i * 16][bcu * 8] = bbuf[i];
        __syncthreads();
        const unsigned short* arow = &As[w * 16 + m][0];
        const unsigned short* brow = &Bs[m][0];
#pragma unroll
        for (int ks = 0; ks < 4; ++ks) {
            short8 av = *(const short8*)(arow + ks * 32 + q * 8);
            const int bo = ks * 32 + q * 8;
            acc0 = __builtin_amdgcn_mfma_f32_16x16x32_bf16(
                av, *(const short8*)(brow + bo), acc0, 0, 0, 0);
            acc1 = __builtin_amdgcn_mfma_f32_16x16x32_bf16(
                av, *(const short8*)(brow + 16 * 136 + bo), acc1, 0, 0, 0);
            acc2 = __builtin_amdgcn_mfma_f32_16x16x32_bf16(
                av, *(const short8*)(brow + 32 * 136 + bo), acc2, 0, 0, 0);
            acc3 = __builtin_amdgcn_mfma_f32_16x16x32_bf16(
                av, *(const short8*)(brow + 48 * 136 + bo), acc3, 0, 0, 0);
        }
        __syncthreads();
    }
    // epilogue: C/D layout col=lane&15, row=q*4+reg
    float as0 = att_s[m], as1 = att_s[16 + m], as2 = att_s[32 + m], as3 = att_s[48 + m];
    float ad0 = att_d[m], ad1 = att_d[16 + m], ad2 = att_d[32 + m], ad3 = att_d[48 + m];
    const int rowb = row0 + w * 16 + q * 4;
#pragma unroll
    for (int rr = 0; rr < 4; ++rr) {
        int row = rowb + rr;
        float v0 = acc0[rr], v1 = acc1[rr], v2 = acc2[rr], v3 = acc3[rr];
        if (row < M) {
            __half* hp = h + (size_t)row * 64 + m;
            hp[0] = __float2half(v0); hp[16] = __float2half(v1);
            hp[32] = __float2half(v2); hp[48] = __float2half(v3);
        }
        float hs = v0 * as0 + v1 * as1 + v2 * as2 + v3 * as3;
        float hd = v0 * ad0 + v1 * ad1 + v2 * ad2 + v3 * ad3;
#pragma unroll
        for (int off = 1; off < 16; off <<= 1) {
            hs += __shfl_xor(hs, off, 64);
            hd += __shfl_xor(hd, off, 64);
        }
        if (m == 0 && row < M) { a_s[row] = hs; a_d[row] = hd; }
    }
}

// ---- Layer-2 GEMM: bf16 MFMA, K=64, no LDS (frags from L2) + fused att ----
__global__ __launch_bounds__(256) void gemm2_mfma(
    const unsigned short* __restrict__ Ab, const unsigned short* __restrict__ Wt2,
    int M, __half* __restrict__ h, const float* __restrict__ att_s,
    const float* __restrict__ att_d, float* __restrict__ a_s,
    float* __restrict__ a_d) {
    const int tid = threadIdx.x;
    const int w = tid >> 6, l = tid & 63, m = l & 15, q = l >> 4;
    const int row0 = blockIdx.x * 64;
    const int r = row0 + w * 16 + m;  // A-frag row
    short8 av0 = {0, 0, 0, 0, 0, 0, 0, 0}, av1 = av0;
    if (r < M) {
        av0 = *(const short8*)(Ab + (size_t)r * 64 + q * 8);
        av1 = *(const short8*)(Ab + (size_t)r * 64 + 32 + q * 8);
    }
    f32x4 acc0 = {0.f, 0.f, 0.f, 0.f}, acc1 = acc0, acc2 = acc0, acc3 = acc0;
    const unsigned short* bp = Wt2 + (size_t)m * 64 + q * 8;
    acc0 = __builtin_amdgcn_mfma_f32_16x16x32_bf16(av0, *(const short8*)(bp), acc0, 0, 0, 0);
    acc0 = __builtin_amdgcn_mfma_f32_16x16x32_bf16(av1, *(const short8*)(bp + 32), acc0, 0, 0, 0);
    acc1 = __builtin_amdgcn_mfma_f32_16x16x32_bf16(av0, *(const short8*)(bp + 16 * 64), acc1, 0, 0, 0);
    acc1 = __builtin_amdgcn_mfma_f32_16x16x32_bf16(av1, *(const short8*)(bp + 16 * 64 + 32), acc1, 0, 0, 0);
    acc2 = __builtin_amdgcn_mfma_f32_16x16x32_bf16(av0, *(const short8*)(bp + 32 * 64), acc2, 0, 0, 0);
    acc2 = __builtin_amdgcn_mfma_f32_16x16x32_bf16(av1, *(const short8*)(bp + 32 * 64 + 32), acc2, 0, 0, 0);
    acc3 = __builtin_amdgcn_mfma_f32_16x16x32_bf16(av0, *(const short8*)(bp + 48 * 64), acc3, 0, 0, 0);
    acc3 = __builtin_amdgcn_mfma_f32_16x16x32_bf16(av1, *(const short8*)(bp + 48 * 64 + 32), acc3, 0, 0, 0);

    float as0 = att_s[m], as1 = att_s[16 + m], as2 = att_s[32 + m], as3 = att_s[48 + m];
    float ad0 = att_d[m], ad1 = att_d[16 + m], ad2 = att_d[32 + m], ad3 = att_d[48 + m];
    const int rowb = row0 + w * 16 + q * 4;
#pragma unroll
    for (int rr = 0; rr < 4; ++rr) {
        int row = rowb + rr;
        float v0 = acc0[rr], v1 = acc1[rr], v2 = acc2[rr], v3 = acc3[rr];
        if (row < M) {
            __half* hp = h + (size_t)row * 64 + m;
            hp[0] = __float2half(v0); hp[16] = __float2half(v1);
            hp[32] = __float2half(v2); hp[48] = __float2half(v3);
        }
        float hs = v0 * as0 + v1 * as1 + v2 * as2 + v3 * as3;
        float hd = v0 * ad0 + v1 * ad1 + v2 * ad2 + v3 * ad3;
#pragma unroll
        for (int off = 1; off < 16; off <<= 1) {
            hs += __shfl_xor(hs, off, 64);
            hd += __shfl_xor(hd, off, 64);
        }
        if (m == 0 && row < M) { a_s[row] = hs; a_d[row] = hd; }
    }
}

// ---- fused edge-softmax + aggregation + bias + relu: one wave per dst node.
// h is FP16 (gather = uint2/8B per lane, 128B per row). Accumulate fp32.
// out (fp32) and outb (bf16) are each optional.
__global__ __launch_bounds__(256) void gat_agg_kernel(
    const int* __restrict__ row_ptr, const int* __restrict__ srcs,
    const float* __restrict__ a_s, const float* __restrict__ a_d,
    const __half* __restrict__ h, const float* __restrict__ bias,
    float* __restrict__ out, unsigned short* __restrict__ outb, int N) {
    int n = blockIdx.x * 4 + (threadIdx.x >> 6);
    int lane = threadIdx.x & 63;
    if (n >= N) return;
    const int start = row_ptr[n];
    const int deg = row_ptr[n + 1] - start;
    const float adn = a_d[n];

    if (deg <= 64) {
        int sl = 0;
        float v = -1e30f;
        if (lane < deg) {
            sl = srcs[start + lane];
            float t = a_s[sl] + adn;
            v = (t >= 0.f) ? t : NEG_SLOPE * t;
        }
        float m = wave_reduce_max(v);
        float wl = (lane < deg) ? __expf(v - m) : 0.f;
        float l = wave_reduce_sum(wl);
        wl *= (1.f / l);

        const int eq = lane >> 4, fq = lane & 15;
        float ax = 0.f, ay = 0.f, az = 0.f, aw = 0.f;
        for (int j = 0; j < deg; j += 4) {
            int idx = j + eq;
            bool ok = idx < deg;
            int ii = ok ? idx : 0;
            float a = __shfl(wl, ii, 64);
            int s = __shfl(sl, ii, 64);
            if (!ok) a = 0.f;
            const uint2 u = *(const uint2*)(h + (size_t)s * 64 + fq * 4);
            const __half2 h01 = *(const __half2*)&u.x;
            const __half2 h23 = *(const __half2*)&u.y;
            const float2 f01 = __half22float2(h01), f23 = __half22float2(h23);
            ax += a * f01.x; ay += a * f01.y; az += a * f23.x; aw += a * f23.y;
        }
#pragma unroll
        for (int off = 16; off <= 32; off <<= 1) {
            ax += __shfl_xor(ax, off, 64);
            ay += __shfl_xor(ay, off, 64);
            az += __shfl_xor(az, off, 64);
            aw += __shfl_xor(aw, off, 64);
        }
        if (eq == 0) {
            const float4 bv = *(const float4*)(bias + fq * 4);
            float4 o;
            o.x = ax + bv.x; o.y = ay + bv.y; o.z = az + bv.z; o.w = aw + bv.w;
            o.x = o.x > 0.f ? o.x : 0.f;
            o.y = o.y > 0.f ? o.y : 0.f;
            o.z = o.z > 0.f ? o.z : 0.f;
            o.w = o.w > 0.f ? o.w : 0.f;
            if (out) *(float4*)(out + (size_t)n * 64 + fq * 4) = o;
            if (outb) {
                unsigned short t[4] = {f2bf(o.x), f2bf(o.y), f2bf(o.z), f2bf(o.w)};
                *(uint2*)(outb + (size_t)n * 64 + fq * 4) = *(uint2*)t;
            }
        }
        return;
    }

    // general path (deg > 64)
    const int end = start + deg;
    float m = -1e30f;
    for (int i = start + lane; i < end; i += 64) {
        float v = a_s[srcs[i]] + adn;
        v = (v >= 0.f) ? v : NEG_SLOPE * v;
        m = fmaxf(m, v);
    }
    m = wave_reduce_max(m);
    float l = 0.f;
    for (int i = start + lane; i < end; i += 64) {
        float v = a_s[srcs[i]] + adn;
        v = (v >= 0.f) ? v : NEG_SLOPE * v;
        l += __expf(v - m);
    }
    l = wave_reduce_sum(l);
    const float inv_den = 1.f / l;
    float acc = 0.f;
    for (int c = start; c < end; c += 64) {
        int cl = end - c;
        if (cl > 64) cl = 64;
        int sl = 0;
        float wl = 0.f;
        if (c + lane < end) {
            sl = srcs[c + lane];
            float v = a_s[sl] + adn;
            v = (v >= 0.f) ? v : NEG_SLOPE * v;
            wl = __expf(v - m) * inv_den;
        }
        for (int j = 0; j < cl; ++j) {
            float wj = __shfl(wl, j, 64);
            int sj = __shfl(sl, j, 64);
            acc += wj * __half2float(h[(size_t)sj * 64 + lane]);
        }
    }
    float o = acc + bias[lane];
    o = o > 0.f ? o : 0.f;
    if (out) out[(size_t)n * 64 + lane] = o;
    if (outb) outb[(size_t)n * 64 + lane] = f2bf(o);
}

// ---- fused mean-pool + final linear: one block (4 waves) per graph ----
__global__ __launch_bounds__(256) void pool_final(const float* __restrict__ x,
                                                  const int* __restrict__ gstart,
                                                  const float* __restrict__ Wlin,
                                                  const float* __restrict__ blin,
                                                  float* __restrict__ out) {
    __shared__ float red[4][64];
    const int g = blockIdx.x;
    const int lane = threadIdx.x & 63, w = threadIdx.x >> 6;
    const int s = gstart[g], e = gstart[g + 1];
    float acc = 0.f;
    for (int n = s + w; n < e; n += 4) acc += x[(size_t)n * 64 + lane];
    red[w][lane] = acc;
    __syncthreads();
    if (w == 0) {
        float p = red[0][lane] + red[1][lane] + red[2][lane] + red[3][lane];
        int c = e - s;
        p /= (float)(c > 1 ? c : 1);
        float o0 = wave_reduce_sum(p * Wlin[lane * 2 + 0]);
        float o1 = wave_reduce_sum(p * Wlin[lane * 2 + 1]);
        if (lane == 0) {
            out[g * 2 + 0] = o0 + blin[0];
            out[g * 2 + 1] = o1 + blin[1];
        }
    }
}

extern "C" void kernel_launch(void* const* d_in, const int* in_sizes, int n_in,
                              void* d_out, int out_size, void* d_ws, size_t ws_size,
                              hipStream_t stream) {
    const float* x    = (const float*)d_in[0];
    const int*   ei   = (const int*)d_in[1];
    const int*   batch= (const int*)d_in[2];
    const float* W1   = (const float*)d_in[3];
    const float* as1  = (const float*)d_in[4];
    const float* ad1  = (const float*)d_in[5];
    const float* b1   = (const float*)d_in[6];
    const float* W2   = (const float*)d_in[7];
    const float* as2  = (const float*)d_in[8];
    const float* ad2  = (const float*)d_in[9];
    const float* b2   = (const float*)d_in[10];
    const float* Wlin = (const float*)d_in[11];
    const float* blin = (const float*)d_in[12];
    float* out = (float*)d_out;

    const int FIN = 768;
    const int N  = in_sizes[0] / FIN;   // 50000
    const int E  = in_sizes[1] / 2;     // 800000
    const int ET = E + N;
    const size_t N64 = (size_t)N * 64;
    const int NB = 64;                  // scan blocks
    const int CH = (N + NB - 1) / NB;

    char* p = (char*)d_ws;
    auto alloc = [&](size_t bytes) {
        char* r = p;
        p += (bytes + 15) & ~(size_t)15;
        return r;
    };
    __half* hb    = (__half*)alloc(N64 * 2);            // N*64 fp16 (h1, then h2)
    float* x2     = (float*)alloc(N64 * 4);             // layer-2 agg output
    float* a_s    = (float*)alloc((size_t)N * 4);
    float* a_d    = (float*)alloc((size_t)N * 4);
    int* counts   = (int*)alloc((size_t)N * 4);         // zeroed
    int* row_ptr  = (int*)alloc((size_t)(N + 1) * 4);
    int* blk_sum  = (int*)alloc(64 * 4);
    int* gstart   = (int*)alloc((NGRAPHS + 1) * 4);
    int* srcs     = (int*)alloc((size_t)ET * 4);
    int* rank     = (int*)alloc((size_t)ET * 4);
    unsigned short* Wt1 = (unsigned short*)alloc((size_t)64 * FIN * 2);
    unsigned short* Wt2 = (unsigned short*)alloc((size_t)64 * 64 * 2);
    unsigned short* x1b = (unsigned short*)alloc(N64 * 2);  // layer-1 out, bf16

    const int nEdgeBlk  = (ET + 255) / 256;
    const int nWaveBlkN = (N + 3) / 4;
    const int nGemmBlk  = (N + 63) / 64;

    hipMemsetAsync(counts, 0, (size_t)N * sizeof(int), stream);

    // ---- setup (W converts, graph bounds) + edge histogram + rank ----
    setup_hist<<<nEdgeBlk + 66, 256, 0, stream>>>(ei, E, ET, counts, nEdgeBlk,
                                                  W1, Wt1, FIN, W2, Wt2,
                                                  batch, gstart, N, rank);
    // ---- row_ptr scan ----
    scan_sum<<<NB, 256, 0, stream>>>(counts, blk_sum, N, CH);
    scan_blk<<<1, 64, 0, stream>>>(blk_sum, row_ptr, N, NB);
    scan_local<<<NB, 256, 0, stream>>>(counts, blk_sum, row_ptr, N, CH);

    // ---- CSR fill (atomic-free) ----
    fill_csr<<<nEdgeBlk, 256, 0, stream>>>(ei, E, ET, row_ptr, rank, srcs);

    // ---- Layer-1 MFMA gemm (coalesced staging) + fused att ----
    gemm1_mfma<<<nGemmBlk, 256, 0, stream>>>(x, Wt1, N, FIN, hb, as1, ad1,
                                             a_s, a_d);
    gat_agg_kernel<<<nWaveBlkN, 256, 0, stream>>>(row_ptr, srcs, a_s, a_d, hb,
                                                  b1, nullptr, x1b, N);

    // ---- Layer-2 MFMA gemm (bf16, no LDS) + fused att ----
    gemm2_mfma<<<nGemmBlk, 256, 0, stream>>>(x1b, Wt2, N, hb, as2, ad2, a_s, a_d);
    gat_agg_kernel<<<nWaveBlkN, 256, 0, stream>>>(row_ptr, srcs, a_s, a_d, hb,
                                                  b2, x2, nullptr, N);

    // ---- Pool + final linear ----
    pool_final<<<NGRAPHS, 256, 0, stream>>>(x2, gstart, Wlin, blin, out);
}

// Round 9
// 402.188 us; speedup vs baseline: 1.0707x; 1.0035x over previous
//
#include <hip/hip_runtime.h>
#include <hip/hip_fp16.h>

#define NEG_SLOPE 0.2f
#define NGRAPHS 512

typedef short short8 __attribute__((ext_vector_type(8)));
typedef float f32x4 __attribute__((ext_vector_type(4)));

__device__ __forceinline__ float wave_reduce_sum(float v) {
#pragma unroll
    for (int off = 32; off > 0; off >>= 1) v += __shfl_xor(v, off, 64);
    return v;
}
__device__ __forceinline__ float wave_reduce_max(float v) {
#pragma unroll
    for (int off = 32; off > 0; off >>= 1) v = fmaxf(v, __shfl_xor(v, off, 64));
    return v;
}
__device__ __forceinline__ unsigned short f2bf(float f) {  // fp32 -> bf16 RNE
    unsigned u = __float_as_uint(f);
    u += 0x7FFFu + ((u >> 16) & 1u);
    return (unsigned short)(u >> 16);
}

__device__ __forceinline__ void edge_sd(const int* __restrict__ ei, int E, int e,
                                        int& s, int& d) {
    if (e < E) { s = ei[e]; d = ei[E + e]; }
    else { s = d = e - E; }  // appended self-loops
}

// ---- setup + histogram, block-specialized:
// blocks [0,nEdgeBlk): hist (also records rank-within-dst); [+64): convert W1;
// [+1): convert W2; [+1): bounds
__global__ __launch_bounds__(256) void setup_hist(
    const int* __restrict__ ei, int E, int ET, int* __restrict__ counts,
    int nEdgeBlk, const float* __restrict__ W1, unsigned short* __restrict__ Wt1,
    int K1, const float* __restrict__ W2, unsigned short* __restrict__ Wt2,
    const int* __restrict__ batch, int* __restrict__ gstart, int N,
    int* __restrict__ rank) {
    const int b = blockIdx.x, tid = threadIdx.x;
    if (b < nEdgeBlk) {
        int e = b * 256 + tid;
        if (e >= ET) return;
        int s, d;
        edge_sd(ei, E, e, s, d);
        rank[e] = atomicAdd(counts + d, 1);  // rank reused by fill_csr: no 2nd atomic pass
    } else if (b < nEdgeBlk + 64) {
        int n = b - nEdgeBlk;
        for (int k = tid; k < K1; k += 256)
            Wt1[(size_t)n * K1 + k] = f2bf(W1[(size_t)k * 64 + n]);
    } else if (b == nEdgeBlk + 64) {
#pragma unroll
        for (int i = 0; i < 16; ++i) {
            int idx = tid + i * 256;
            int n = idx >> 6, k = idx & 63;
            Wt2[n * 64 + k] = f2bf(W2[k * 64 + n]);
        }
    } else {
        for (int g = tid; g <= NGRAPHS; g += 256) {
            int lo = 0, hi = N;
            while (lo < hi) {
                int mid = (lo + hi) >> 1;
                if (batch[mid] < g) lo = mid + 1; else hi = mid;
            }
            gstart[g] = lo;
        }
    }
}

// per-block sums over chunks of CH
__global__ __launch_bounds__(256) void scan_sum(const int* __restrict__ counts,
                                                int* __restrict__ blk_sum, int N,
                                                int CH) {
    __shared__ int wsum[4];
    const int tid = threadIdx.x, lane = tid & 63, wid = tid >> 6;
    const int b = blockIdx.x;
    int begin = b * CH, endi = min(begin + CH, N);
    int s = 0;
    for (int i = begin + tid; i < endi; i += 256) s += counts[i];
#pragma unroll
    for (int off = 32; off > 0; off >>= 1) s += __shfl_xor(s, off, 64);
    if (lane == 0) wsum[wid] = s;
    __syncthreads();
    if (tid == 0) blk_sum[b] = wsum[0] + wsum[1] + wsum[2] + wsum[3];
}

// exclusive scan of 64 block sums (1 wave); also writes row_ptr[N]=total
__global__ __launch_bounds__(64) void scan_blk(int* __restrict__ blk_sum,
                                               int* __restrict__ row_ptr, int N,
                                               int nb) {
    int t = threadIdx.x;
    int v = (t < nb) ? blk_sum[t] : 0;
    int sv = v;
#pragma unroll
    for (int off = 1; off < 64; off <<= 1) {
        int u = __shfl_up(sv, off, 64);
        if (t >= off) sv += u;
    }
    if (t < nb) blk_sum[t] = sv - v;
    if (t == nb - 1) row_ptr[N] = sv;
}

// local exclusive scan with block offset; writes row_ptr
__global__ __launch_bounds__(256) void scan_local(const int* __restrict__ counts,
                                                  const int* __restrict__ blk_off,
                                                  int* __restrict__ row_ptr, int N,
                                                  int CH) {
    __shared__ int wsum[4];
    __shared__ int ctot;
    const int tid = threadIdx.x, lane = tid & 63, wid = tid >> 6;
    const int b = blockIdx.x;
    int begin = b * CH, endi = min(begin + CH, N);
    int carry = blk_off[b];
    for (int base = begin; base < endi; base += 256) {
        int i = base + tid;
        int v = (i < endi) ? counts[i] : 0;
        int sv = v;
#pragma unroll
        for (int off = 1; off < 64; off <<= 1) {
            int u = __shfl_up(sv, off, 64);
            if (lane >= off) sv += u;
        }
        if (lane == 63) wsum[wid] = sv;
        __syncthreads();
        if (tid == 0) {
            int a = 0;
#pragma unroll
            for (int j = 0; j < 4; ++j) { int u = wsum[j]; wsum[j] = a; a += u; }
            ctot = a;
        }
        __syncthreads();
        int excl = carry + wsum[wid] + sv - v;
        if (i < endi) row_ptr[i] = excl;
        carry += ctot;
        __syncthreads();
    }
}

// ---- CSR fill, atomic-free: pos = row_ptr[dst] + rank (from hist pass) ----
__global__ __launch_bounds__(256) void fill_csr(const int* __restrict__ ei, int E,
                                                int ET,
                                                const int* __restrict__ row_ptr,
                                                const int* __restrict__ rank,
                                                int* __restrict__ srcs) {
    int e = blockIdx.x * 256 + threadIdx.x;
    if (e >= ET) return;
    int s, d;
    edge_sd(ei, E, e, s, d);
    srcs[row_ptr[d] + rank[e]] = s;
}

// ---- Layer-1 GEMM (bf16 MFMA) + fused att epilogue. COALESCED staging
// (R5 structure). h written in FP16.
__global__ __launch_bounds__(256, 4) void gemm1_mfma(
    const float* __restrict__ A, const unsigned short* __restrict__ Wt, int M,
    int K, __half* __restrict__ h, const float* __restrict__ att_s,
    const float* __restrict__ att_d, float* __restrict__ a_s,
    float* __restrict__ a_d) {
    __shared__ unsigned short As[64][136];  // A chunk, bf16 (17.4 KB)
    __shared__ unsigned short Bs[64][136];  // B chunk, bf16 (17.4 KB)
    const int tid = threadIdx.x;
    const int w = tid >> 6, l = tid & 63, m = l & 15, q = l >> 4;
    const int row0 = blockIdx.x * 64;
    // A staging: 64 rows x 128 fp32/chunk; wave = 2 contiguous 512B spans.
    const int sr = tid >> 5;   // 0..7
    const int sc4 = tid & 31;  // float4 within 128-float row-slice
    int srow[8];
#pragma unroll
    for (int i = 0; i < 8; ++i) {
        int r = row0 + sr + i * 8;
        srow[i] = r < M ? r : M - 1;  // clamp; garbage rows are store-masked
    }
    // B staging: 64 rows x 128 bf16/chunk; wave = 4 contiguous 256B spans.
    const int br = tid >> 4;   // 0..15
    const int bcu = tid & 15;  // uint4 (8 bf16) within row-slice
    f32x4 acc0 = {0.f, 0.f, 0.f, 0.f}, acc1 = acc0, acc2 = acc0, acc3 = acc0;
#pragma unroll 1
    for (int c = 0; c < 6; ++c) {  // K = 768 = 6 chunks of 128
        float4 abuf[8];
#pragma unroll
        for (int i = 0; i < 8; ++i)
            abuf[i] = *(const float4*)(A + (size_t)srow[i] * K + c * 128 + sc4 * 4);
        uint4 bbuf[4];
#pragma unroll
        for (int i = 0; i < 4; ++i)
            bbuf[i] = *(const uint4*)(Wt + (size_t)(br + i * 16) * K + c * 128 + bcu * 8);
#pragma unroll
        for (int i = 0; i < 8; ++i) {
            unsigned short t4[4] = {f2bf(abuf[i].x), f2bf(abuf[i].y),
                                    f2bf(abuf[i].z), f2bf(abuf[i].w)};
            *(uint2*)&As[sr + i * 8][sc4 * 4] = *(uint2*)t4;
        }
#pragma unroll
        for (int i = 0; i < 4; ++i)
            *(uint4*)&Bs[br + i * 16][bcu * 8] = bbuf[i];
        __syncthreads();
        const unsigned short* arow = &As[w * 16 + m][0];
        const unsigned short* brow = &Bs[m][0];
#pragma unroll
        for (int ks = 0; ks < 4; ++ks) {
            short8 av = *(const short8*)(arow + ks * 32 + q * 8);
            const int bo = ks * 32 + q * 8;
            acc0 = __builtin_amdgcn_mfma_f32_16x16x32_bf16(
                av, *(const short8*)(brow + bo), acc0, 0, 0, 0);
            acc1 = __builtin_amdgcn_mfma_f32_16x16x32_bf16(
                av, *(const short8*)(brow + 16 * 136 + bo), acc1, 0, 0, 0);
            acc2 = __builtin_amdgcn_mfma_f32_16x16x32_bf16(
                av, *(const short8*)(brow + 32 * 136 + bo), acc2, 0, 0, 0);
            acc3 = __builtin_amdgcn_mfma_f32_16x16x32_bf16(
                av, *(const short8*)(brow + 48 * 136 + bo), acc3, 0, 0, 0);
        }
        __syncthreads();
    }
    // epilogue: C/D layout col=lane&15, row=q*4+reg
    float as0 = att_s[m], as1 = att_s[16 + m], as2 = att_s[32 + m], as3 = att_s[48 + m];
    float ad0 = att_d[m], ad1 = att_d[16 + m], ad2 = att_d[32 + m], ad3 = att_d[48 + m];
    const int rowb = row0 + w * 16 + q * 4;
#pragma unroll
    for (int rr = 0; rr < 4; ++rr) {
        int row = rowb + rr;
        float v0 = acc0[rr], v1 = acc1[rr], v2 = acc2[rr], v3 = acc3[rr];
        if (row < M) {
            __half* hp = h + (size_t)row * 64 + m;
            hp[0] = __float2half(v0); hp[16] = __float2half(v1);
            hp[32] = __float2half(v2); hp[48] = __float2half(v3);
        }
        float hs = v0 * as0 + v1 * as1 + v2 * as2 + v3 * as3;
        float hd = v0 * ad0 + v1 * ad1 + v2 * ad2 + v3 * ad3;
#pragma unroll
        for (int off = 1; off < 16; off <<= 1) {
            hs += __shfl_xor(hs, off, 64);
            hd += __shfl_xor(hd, off, 64);
        }
        if (m == 0 && row < M) { a_s[row] = hs; a_d[row] = hd; }
    }
}

// ---- Layer-2 GEMM: bf16 MFMA, K=64, no LDS (frags from L2) + fused att ----
__global__ __launch_bounds__(256) void gemm2_mfma(
    const unsigned short* __restrict__ Ab, const unsigned short* __restrict__ Wt2,
    int M, __half* __restrict__ h, const float* __restrict__ att_s,
    const float* __restrict__ att_d, float* __restrict__ a_s,
    float* __restrict__ a_d) {
    const int tid = threadIdx.x;
    const int w = tid >> 6, l = tid & 63, m = l & 15, q = l >> 4;
    const int row0 = blockIdx.x * 64;
    const int r = row0 + w * 16 + m;  // A-frag row
    short8 av0 = {0, 0, 0, 0, 0, 0, 0, 0}, av1 = av0;
    if (r < M) {
        av0 = *(const short8*)(Ab + (size_t)r * 64 + q * 8);
        av1 = *(const short8*)(Ab + (size_t)r * 64 + 32 + q * 8);
    }
    f32x4 acc0 = {0.f, 0.f, 0.f, 0.f}, acc1 = acc0, acc2 = acc0, acc3 = acc0;
    const unsigned short* bp = Wt2 + (size_t)m * 64 + q * 8;
    acc0 = __builtin_amdgcn_mfma_f32_16x16x32_bf16(av0, *(const short8*)(bp), acc0, 0, 0, 0);
    acc0 = __builtin_amdgcn_mfma_f32_16x16x32_bf16(av1, *(const short8*)(bp + 32), acc0, 0, 0, 0);
    acc1 = __builtin_amdgcn_mfma_f32_16x16x32_bf16(av0, *(const short8*)(bp + 16 * 64), acc1, 0, 0, 0);
    acc1 = __builtin_amdgcn_mfma_f32_16x16x32_bf16(av1, *(const short8*)(bp + 16 * 64 + 32), acc1, 0, 0, 0);
    acc2 = __builtin_amdgcn_mfma_f32_16x16x32_bf16(av0, *(const short8*)(bp + 32 * 64), acc2, 0, 0, 0);
    acc2 = __builtin_amdgcn_mfma_f32_16x16x32_bf16(av1, *(const short8*)(bp + 32 * 64 + 32), acc2, 0, 0, 0);
    acc3 = __builtin_amdgcn_mfma_f32_16x16x32_bf16(av0, *(const short8*)(bp + 48 * 64), acc3, 0, 0, 0);
    acc3 = __builtin_amdgcn_mfma_f32_16x16x32_bf16(av1, *(const short8*)(bp + 48 * 64 + 32), acc3, 0, 0, 0);

    float as0 = att_s[m], as1 = att_s[16 + m], as2 = att_s[32 + m], as3 = att_s[48 + m];
    float ad0 = att_d[m], ad1 = att_d[16 + m], ad2 = att_d[32 + m], ad3 = att_d[48 + m];
    const int rowb = row0 + w * 16 + q * 4;
#pragma unroll
    for (int rr = 0; rr < 4; ++rr) {
        int row = rowb + rr;
        float v0 = acc0[rr], v1 = acc1[rr], v2 = acc2[rr], v3 = acc3[rr];
        if (row < M) {
            __half* hp = h + (size_t)row * 64 + m;
            hp[0] = __float2half(v0); hp[16] = __float2half(v1);
            hp[32] = __float2half(v2); hp[48] = __float2half(v3);
        }
        float hs = v0 * as0 + v1 * as1 + v2 * as2 + v3 * as3;
        float hd = v0 * ad0 + v1 * ad1 + v2 * ad2 + v3 * ad3;
#pragma unroll
        for (int off = 1; off < 16; off <<= 1) {
            hs += __shfl_xor(hs, off, 64);
            hd += __shfl_xor(hd, off, 64);
        }
        if (m == 0 && row < M) { a_s[row] = hs; a_d[row] = hd; }
    }
}

// ---- fused edge-softmax + aggregation + bias + relu: one wave per dst node.
// h is FP16. T14-style: the first 8 h-row loads are issued BEFORE the softmax
// shfl-reduce chain (addresses depend only on sl), and the gather loop is
// unrolled to 8 edges/iter with rotating prefetch -> 8 rows in flight, load
// latency hidden under reduces/FMAs. No barriers in this kernel, so the
// scheduler keeps the hoisted loads early.
__global__ __launch_bounds__(256) void gat_agg_kernel(
    const int* __restrict__ row_ptr, const int* __restrict__ srcs,
    const float* __restrict__ a_s, const float* __restrict__ a_d,
    const __half* __restrict__ h, const float* __restrict__ bias,
    float* __restrict__ out, unsigned short* __restrict__ outb, int N) {
    int n = blockIdx.x * 4 + (threadIdx.x >> 6);
    int lane = threadIdx.x & 63;
    if (n >= N) return;
    const int start = row_ptr[n];
    const int deg = row_ptr[n + 1] - start;
    const float adn = a_d[n];

    if (deg <= 64) {
        int sl = 0;
        float v = -1e30f;
        if (lane < deg) {
            sl = srcs[start + lane];
            float t = a_s[sl] + adn;
            v = (t >= 0.f) ? t : NEG_SLOPE * t;
        }
        const int eq = lane >> 4, fq = lane & 15;
        // prefetch rows for edges {eq, 4+eq} NOW; they fly under the reduces
        int ci0 = eq, ci1 = 4 + eq;
        bool cok0 = ci0 < deg, cok1 = ci1 < deg;
        int cs0 = __shfl(sl, cok0 ? ci0 : 0, 64);
        int cs1 = __shfl(sl, cok1 ? ci1 : 0, 64);
        uint2 cu0 = *(const uint2*)(h + (size_t)cs0 * 64 + fq * 4);
        uint2 cu1 = *(const uint2*)(h + (size_t)cs1 * 64 + fq * 4);

        float m = wave_reduce_max(v);
        float wl = (lane < deg) ? __expf(v - m) : 0.f;
        float l = wave_reduce_sum(wl);
        wl *= (1.f / l);

        float ax = 0.f, ay = 0.f, az = 0.f, aw = 0.f;
        for (int j = 0; j < deg; j += 8) {
            float a0 = __shfl(wl, cok0 ? ci0 : 0, 64);
            float a1 = __shfl(wl, cok1 ? ci1 : 0, 64);
            if (!cok0) a0 = 0.f;
            if (!cok1) a1 = 0.f;
            // prefetch next 8 edges' rows (clamped addresses always valid)
            int ni0 = j + 8 + eq, ni1 = j + 12 + eq;
            bool nok0 = ni0 < deg, nok1 = ni1 < deg;
            int ns0 = __shfl(sl, nok0 ? ni0 : 0, 64);
            int ns1 = __shfl(sl, nok1 ? ni1 : 0, 64);
            uint2 nu0 = *(const uint2*)(h + (size_t)ns0 * 64 + fq * 4);
            uint2 nu1 = *(const uint2*)(h + (size_t)ns1 * 64 + fq * 4);
            const __half2 p01 = *(const __half2*)&cu0.x;
            const __half2 p23 = *(const __half2*)&cu0.y;
            const __half2 q01 = *(const __half2*)&cu1.x;
            const __half2 q23 = *(const __half2*)&cu1.y;
            const float2 f01 = __half22float2(p01), f23 = __half22float2(p23);
            const float2 g01 = __half22float2(q01), g23 = __half22float2(q23);
            ax += a0 * f01.x + a1 * g01.x;
            ay += a0 * f01.y + a1 * g01.y;
            az += a0 * f23.x + a1 * g23.x;
            aw += a0 * f23.y + a1 * g23.y;
            cu0 = nu0; cu1 = nu1;
            ci0 = ni0; ci1 = ni1;
            cok0 = nok0; cok1 = nok1;
        }
#pragma unroll
        for (int off = 16; off <= 32; off <<= 1) {
            ax += __shfl_xor(ax, off, 64);
            ay += __shfl_xor(ay, off, 64);
            az += __shfl_xor(az, off, 64);
            aw += __shfl_xor(aw, off, 64);
        }
        if (eq == 0) {
            const float4 bv = *(const float4*)(bias + fq * 4);
            float4 o;
            o.x = ax + bv.x; o.y = ay + bv.y; o.z = az + bv.z; o.w = aw + bv.w;
            o.x = o.x > 0.f ? o.x : 0.f;
            o.y = o.y > 0.f ? o.y : 0.f;
            o.z = o.z > 0.f ? o.z : 0.f;
            o.w = o.w > 0.f ? o.w : 0.f;
            if (out) *(float4*)(out + (size_t)n * 64 + fq * 4) = o;
            if (outb) {
                unsigned short t[4] = {f2bf(o.x), f2bf(o.y), f2bf(o.z), f2bf(o.w)};
                *(uint2*)(outb + (size_t)n * 64 + fq * 4) = *(uint2*)t;
            }
        }
        return;
    }

    // general path (deg > 64)
    const int end = start + deg;
    float m = -1e30f;
    for (int i = start + lane; i < end; i += 64) {
        float v = a_s[srcs[i]] + adn;
        v = (v >= 0.f) ? v : NEG_SLOPE * v;
        m = fmaxf(m, v);
    }
    m = wave_reduce_max(m);
    float l = 0.f;
    for (int i = start + lane; i < end; i += 64) {
        float v = a_s[srcs[i]] + adn;
        v = (v >= 0.f) ? v : NEG_SLOPE * v;
        l += __expf(v - m);
    }
    l = wave_reduce_sum(l);
    const float inv_den = 1.f / l;
    float acc = 0.f;
    for (int c = start; c < end; c += 64) {
        int cl = end - c;
        if (cl > 64) cl = 64;
        int sl = 0;
        float wl = 0.f;
        if (c + lane < end) {
            sl = srcs[c + lane];
            float v = a_s[sl] + adn;
            v = (v >= 0.f) ? v : NEG_SLOPE * v;
            wl = __expf(v - m) * inv_den;
        }
        for (int j = 0; j < cl; ++j) {
            float wj = __shfl(wl, j, 64);
            int sj = __shfl(sl, j, 64);
            acc += wj * __half2float(h[(size_t)sj * 64 + lane]);
        }
    }
    float o = acc + bias[lane];
    o = o > 0.f ? o : 0.f;
    if (out) out[(size_t)n * 64 + lane] = o;
    if (outb) outb[(size_t)n * 64 + lane] = f2bf(o);
}

// ---- fused mean-pool + final linear: one block (4 waves) per graph ----
__global__ __launch_bounds__(256) void pool_final(const float* __restrict__ x,
                                                  const int* __restrict__ gstart,
                                                  const float* __restrict__ Wlin,
                                                  const float* __restrict__ blin,
                                                  float* __restrict__ out) {
    __shared__ float red[4][64];
    const int g = blockIdx.x;
    const int lane = threadIdx.x & 63, w = threadIdx.x >> 6;
    const int s = gstart[g], e = gstart[g + 1];
    float acc = 0.f;
    for (int n = s + w; n < e; n += 4) acc += x[(size_t)n * 64 + lane];
    red[w][lane] = acc;
    __syncthreads();
    if (w == 0) {
        float p = red[0][lane] + red[1][lane] + red[2][lane] + red[3][lane];
        int c = e - s;
        p /= (float)(c > 1 ? c : 1);
        float o0 = wave_reduce_sum(p * Wlin[lane * 2 + 0]);
        float o1 = wave_reduce_sum(p * Wlin[lane * 2 + 1]);
        if (lane == 0) {
            out[g * 2 + 0] = o0 + blin[0];
            out[g * 2 + 1] = o1 + blin[1];
        }
    }
}

extern "C" void kernel_launch(void* const* d_in, const int* in_sizes, int n_in,
                              void* d_out, int out_size, void* d_ws, size_t ws_size,
                              hipStream_t stream) {
    const float* x    = (const float*)d_in[0];
    const int*   ei   = (const int*)d_in[1];
    const int*   batch= (const int*)d_in[2];
    const float* W1   = (const float*)d_in[3];
    const float* as1  = (const float*)d_in[4];
    const float* ad1  = (const float*)d_in[5];
    const float* b1   = (const float*)d_in[6];
    const float* W2   = (const float*)d_in[7];
    const float* as2  = (const float*)d_in[8];
    const float* ad2  = (const float*)d_in[9];
    const float* b2   = (const float*)d_in[10];
    const float* Wlin = (const float*)d_in[11];
    const float* blin = (const float*)d_in[12];
    float* out = (float*)d_out;

    const int FIN = 768;
    const int N  = in_sizes[0] / FIN;   // 50000
    const int E  = in_sizes[1] / 2;     // 800000
    const int ET = E + N;
    const size_t N64 = (size_t)N * 64;
    const int NB = 64;                  // scan blocks
    const int CH = (N + NB - 1) / NB;

    char* p = (char*)d_ws;
    auto alloc = [&](size_t bytes) {
        char* r = p;
        p += (bytes + 15) & ~(size_t)15;
        return r;
    };
    __half* hb    = (__half*)alloc(N64 * 2);            // N*64 fp16 (h1, then h2)
    float* x2     = (float*)alloc(N64 * 4);             // layer-2 agg output
    float* a_s    = (float*)alloc((size_t)N * 4);
    float* a_d    = (float*)alloc((size_t)N * 4);
    int* counts   = (int*)alloc((size_t)N * 4);         // zeroed
    int* row_ptr  = (int*)alloc((size_t)(N + 1) * 4);
    int* blk_sum  = (int*)alloc(64 * 4);
    int* gstart   = (int*)alloc((NGRAPHS + 1) * 4);
    int* srcs     = (int*)alloc((size_t)ET * 4);
    int* rank     = (int*)alloc((size_t)ET * 4);
    unsigned short* Wt1 = (unsigned short*)alloc((size_t)64 * FIN * 2);
    unsigned short* Wt2 = (unsigned short*)alloc((size_t)64 * 64 * 2);
    unsigned short* x1b = (unsigned short*)alloc(N64 * 2);  // layer-1 out, bf16

    const int nEdgeBlk  = (ET + 255) / 256;
    const int nWaveBlkN = (N + 3) / 4;
    const int nGemmBlk  = (N + 63) / 64;

    hipMemsetAsync(counts, 0, (size_t)N * sizeof(int), stream);

    // ---- setup (W converts, graph bounds) + edge histogram + rank ----
    setup_hist<<<nEdgeBlk + 66, 256, 0, stream>>>(ei, E, ET, counts, nEdgeBlk,
                                                  W1, Wt1, FIN, W2, Wt2,
                                                  batch, gstart, N, rank);
    // ---- row_ptr scan ----
    scan_sum<<<NB, 256, 0, stream>>>(counts, blk_sum, N, CH);
    scan_blk<<<1, 64, 0, stream>>>(blk_sum, row_ptr, N, NB);
    scan_local<<<NB, 256, 0, stream>>>(counts, blk_sum, row_ptr, N, CH);

    // ---- CSR fill (atomic-free) ----
    fill_csr<<<nEdgeBlk, 256, 0, stream>>>(ei, E, ET, row_ptr, rank, srcs);

    // ---- Layer-1 MFMA gemm (coalesced staging) + fused att ----
    gemm1_mfma<<<nGemmBlk, 256, 0, stream>>>(x, Wt1, N, FIN, hb, as1, ad1,
                                             a_s, a_d);
    gat_agg_kernel<<<nWaveBlkN, 256, 0, stream>>>(row_ptr, srcs, a_s, a_d, hb,
                                                  b1, nullptr, x1b, N);

    // ---- Layer-2 MFMA gemm (bf16, no LDS) + fused att ----
    gemm2_mfma<<<nGemmBlk, 256, 0, stream>>>(x1b, Wt2, N, hb, as2, ad2, a_s, a_d);
    gat_agg_kernel<<<nWaveBlkN, 256, 0, stream>>>(row_ptr, srcs, a_s, a_d, hb,
                                                  b2, x2, nullptr, N);

    // ---- Pool + final linear ----
    pool_final<<<NGRAPHS, 256, 0, stream>>>(x2, gstart, Wlin, blin, out);
}